// Round 13
// baseline (193.792 us; speedup 1.0000x reference)
//
#include <hip/hip_runtime.h>
#include <stdint.h>

// Batched tiny MLP [B,13]->16->(30x 16->16 relu)->1, fp32 in/out, f16 MFMA.
// Transposed formulation: mfma_f32_16x16x16_f16 D layout == B layout, so each
// layer's relu'd output is the next layer's B fragment in-register.
// R13: ILP discriminator. R12 (6->8 waves/SIMD) was flat => TLP is not the
// limiter. This round doubles per-wave independent work instead: T=8 tiles
// per wave per iteration (8 independent MFMAs + 32 independent relu ops per
// layer), halving iteration count -- total instructions/SIMD unchanged, but
// dependency stalls amortized over 2x work. 71.8KB LDS = 2 blocks/CU = 4
// waves/SIMD (proven sufficient); launch_bounds(512,4) = 128-VGPR budget.

typedef __attribute__((ext_vector_type(4))) _Float16 half4v;
typedef __attribute__((ext_vector_type(2))) _Float16 h2;
typedef __attribute__((ext_vector_type(4))) float float4v;

#define S_IN 13
#define H 16
#define NL 32            // mfma layers: 0 = input, 1..30 = hidden, 31 = output
#define TPB 512
#define WPB 8            // waves per block
#define T 8              // 16-sample tiles per wave per iteration
#define NBLOCKS 512      // 2 blocks/CU * 256 CUs (LDS-limited residency)
#define STRIDE (NBLOCKS * WPB * T)   // tiles per grid sweep = 32768

// per-wave staging: 8 tiles * 208 dwords = 1664 dwords + 4 zero pad
#define XS_DW 1668
// LDS dword map:
//   [0, 4096)            A-frags: 2 dwords (4 f16) per (L, lane)
//   [4096, 4608)         bias[L][m] fp32 (C-operand order)
//   [4608, ...)          per-wave x staging
#define XS_BASE 4608
#define LDS_DW (XS_BASE + WPB * XS_DW)

__device__ __forceinline__ unsigned pkh(float a, float b) {
    return __builtin_bit_cast(unsigned, __builtin_amdgcn_cvt_pkrtz(a, b));
}

__device__ __forceinline__ half4v pack4h(float v0, float v1, float v2, float v3) {
    int2 p;
    p.x = (int)pkh(v0, v1);
    p.y = (int)pkh(v2, v3);
    return __builtin_bit_cast(half4v, p);
}

// cvt then packed-f16 relu: 2 cvt + 2 v_pk_max_f16
__device__ __forceinline__ half4v relu_pack4h(const float4v& d) {
    const h2 z = {(_Float16)0.f, (_Float16)0.f};
    h2 lo = __builtin_bit_cast(h2, pkh(d[0], d[1]));
    h2 hi = __builtin_bit_cast(h2, pkh(d[2], d[3]));
    lo = __builtin_elementwise_max(lo, z);
    hi = __builtin_elementwise_max(hi, z);
    int2 p;
    p.x = __builtin_bit_cast(int, lo);
    p.y = __builtin_bit_cast(int, hi);
    return __builtin_bit_cast(half4v, p);
}

__global__ __launch_bounds__(TPB, 4)
void mlp_kernel(const float* __restrict__ x,
                const float* __restrict__ W_in, const float* __restrict__ b_in,
                const float* __restrict__ W_h,  const float* __restrict__ b_h,
                const float* __restrict__ W_out,const float* __restrict__ b_out,
                float* __restrict__ out, int tiles)
{
    __shared__ unsigned lds[LDS_DW];
    const int tid = threadIdx.x;

    // ---- swizzle weights into f16 A-fragment layout in LDS (once/block) ----
    for (int s = tid; s < NL * 64; s += TPB) {
        const int L = s >> 6, ln = s & 63, m = ln & 15, gg = ln >> 4;
        float v[4];
#pragma unroll
        for (int i = 0; i < 4; ++i) {
            const int k = 4 * gg + i;
            if (L == 0)       v[i] = (k < S_IN) ? W_in[m * S_IN + k] : 0.f;
            else if (L <= 30) v[i] = W_h[(L - 1) * H * H + m * H + k];
            else              v[i] = (m == 0) ? W_out[k] : 0.f;
        }
        lds[s * 2]     = pkh(v[0], v[1]);
        lds[s * 2 + 1] = pkh(v[2], v[3]);
    }
    for (int s = tid; s < NL * H; s += TPB) {
        const int L = s >> 4, m = s & 15;
        float bv;
        if (L == 0)       bv = b_in[m];
        else if (L <= 30) bv = b_h[(L - 1) * H + m];
        else              bv = (m == 0) ? b_out[0] : 0.f;
        lds[4096 + s] = __float_as_uint(bv);
    }
    __syncthreads();

    const half4v* lA = (const half4v*)lds;             // [NL*64], 8B elems
    const float4v* lB = (const float4v*)(lds + 4096);  // [NL*4]

    const int lane = tid & 63;
    const int wv   = tid >> 6;
    const int g    = lane >> 4;
    const int col  = lane & 15;
    const int k0   = 4 * g;
    const int col13k = col * 13 + k0;

    unsigned* xs = lds + XS_BASE + wv * XS_DW;         // wave-private staging
    if (lane < 4) xs[1664 + lane] = 0;                 // zero overshoot pad

    const int wave_id = blockIdx.x * WPB + wv;
    int tb = wave_id * T;
    if (tb >= tiles) return;

    float* op = out + (size_t)tb * 16 + lane;

    // prefetch first iteration's x block (8 tiles = 1664 dwords, coalesced):
    // 6x float4 + 1x float2 per lane
    const float* xp = x + (size_t)tb * 208;
    float4v r[6];
    float2  r6;
#pragma unroll
    for (int i = 0; i < 6; ++i) r[i] = *(const float4v*)(xp + i * 256 + lane * 4);
    r6 = *(const float2*)(xp + 1536 + lane * 2);

    for (; tb < tiles; tb += STRIDE) {
        // stage current x block (wave-private: no barrier needed)
#pragma unroll
        for (int i = 0; i < 6; ++i) *(float4v*)(xs + i * 256 + lane * 4) = r[i];
        *(float2*)(xs + 1536 + lane * 2) = r6;

        // issue next iteration's global loads (in flight across layer chain)
        const int tbn = tb + STRIDE;
        if (tbn < tiles) {
            xp = x + (size_t)tbn * 208;
#pragma unroll
            for (int i = 0; i < 6; ++i) r[i] = *(const float4v*)(xp + i * 256 + lane * 4);
            r6 = *(const float2*)(xp + 1536 + lane * 2);
        }

        // input-layer B fragments (stride-13 dword gather: conflict-free).
        // k slots 13..15 read neighbor x / zero pad: finite, A there is 0.
        half4v bf[T];
#pragma unroll
        for (int t = 0; t < T; ++t) {
            const unsigned* p = xs + t * 208 + col13k;
            bf[t] = pack4h(__uint_as_float(p[0]), __uint_as_float(p[1]),
                           __uint_as_float(p[2]), __uint_as_float(p[3]));
        }

        // ---- 31 layers, A/bias prefetched one ahead; bias rides in C ----
        half4v aC = lA[lane];              // layer 0
        float4v cC = lB[g];
#pragma unroll
        for (int L = 0; L < NL - 1; ++L) {
            const half4v aN = lA[(L + 1) * 64 + lane];
            const float4v cN = lB[(L + 1) * 4 + g];
            float4v d[T];
#pragma unroll
            for (int t = 0; t < T; ++t)
                d[t] = __builtin_amdgcn_mfma_f32_16x16x16f16(aC, bf[t], cC, 0, 0, 0);
#pragma unroll
            for (int t = 0; t < T; ++t)
                bf[t] = relu_pack4h(d[t]);
            aC = aN;
            cC = cN;
        }

        // output layer: W_out lives in row 0 only; y[n] = D[0][n]
#pragma unroll
        for (int t = 0; t < T; ++t) {
            float4v d = __builtin_amdgcn_mfma_f32_16x16x16f16(aC, bf[t], cC, 0, 0, 0);
            if (lane < 16) op[t * 16] = d[0];
        }
        op += (size_t)STRIDE * 16;
    }
}

extern "C" void kernel_launch(void* const* d_in, const int* in_sizes, int n_in,
                              void* d_out, int out_size, void* d_ws, size_t ws_size,
                              hipStream_t stream) {
    const float* x     = (const float*)d_in[0];
    const float* W_in  = (const float*)d_in[1];
    const float* b_in  = (const float*)d_in[2];
    const float* W_h   = (const float*)d_in[3];
    const float* b_h   = (const float*)d_in[4];
    const float* W_out = (const float*)d_in[5];
    const float* b_out = (const float*)d_in[6];
    float* out = (float*)d_out;

    const int tiles = out_size / 16;                       // 131072
    int blocks = (tiles + WPB * T - 1) / (WPB * T);
    if (blocks > NBLOCKS) blocks = NBLOCKS;
    mlp_kernel<<<blocks, TPB, 0, stream>>>(x, W_in, b_in, W_h, b_h, W_out, b_out,
                                           out, tiles);
}